// Round 15
// baseline (547.932 us; speedup 1.0000x reference)
//
#include <hip/hip_runtime.h>

#define SEQ   120
#define WARM  96
#define FLEN  24
#define HDIM  256

typedef __attribute__((ext_vector_type(8))) short bf16x8;
typedef __attribute__((ext_vector_type(4))) float floatx4;
typedef __attribute__((ext_vector_type(4))) unsigned int uintx4;
typedef unsigned int uint;
typedef unsigned long long ull;

// ws layout (bytes):
//   WHI  [0, 512K)        bf16 frag-linear W-hi
//   WLO  [512K, 1M)       bf16 frag-linear W-lo
//   BB   [1M, +4K)        f32 b_ih+b_hh
//   WI   [1M+4K, +4K)     f32 W_ih col
//   BAR  [1M+8K, +8K)     uint bar[2048] (whole region zeroed by prep)
//                         v1 (64-row rg): stride 64; +0 step, +16 init, +32.. xcc
//                         v2 (32-row rg): stride 32; +0 step, +8 init, +16.. xcc
//   HG   [1M+16K, +4M)    uint h packed (hi<<16|lo), 2 parities x 2048 rows x 256k
//                         frag-linear within an rg block of RGROWS*256 uints:
//                         idx = (((rt*8+kt)*4+kq)*16+rlow)*8+kk
//   XT   [5M+16K, +960K)  f32 x transposed [t][row]
#define WHI_OFF 0
#define WLO_OFF (512 * 1024)
#define BB_OFF  (1024 * 1024)
#define WI_OFF  (1024 * 1024 + 4096)
#define BAR_OFF (1024 * 1024 + 8192)
#define HG_OFF  (1024 * 1024 + 16384)
#define HG_PAR  524288              // uints per parity (2048 rows x 256 k)
#define XT_OFF  (HG_OFF + 4 * 1024 * 1024)

#define LDS_BYTES 66816             // wlo 64K | fcw 1K | y 256B

__device__ __forceinline__ short f2bf(float v) {
    unsigned u = __float_as_uint(v);
    u += 0x7FFF + ((u >> 16) & 1);              // RNE
    return (short)(u >> 16);
}
__device__ __forceinline__ float bf2f(short s) {
    return __uint_as_float(((unsigned)(unsigned short)s) << 16);
}
__device__ __forceinline__ float fast_rcp(float x) {
    return __builtin_amdgcn_rcpf(x);
}
__device__ __forceinline__ float fast_sig(float x) {
    return fast_rcp(1.0f + __expf(-x));
}
__device__ __forceinline__ float fast_tanh(float x) {
    return 1.0f - 2.0f * fast_rcp(__expf(2.0f * x) + 1.0f);
}

// ---- LLC-coherent (cross-XCD) helpers: agent scope -> device SC bits ----
__device__ __forceinline__ uint load_llc32u(const uint* p) {
    return __hip_atomic_load(p, __ATOMIC_RELAXED, __HIP_MEMORY_SCOPE_AGENT);
}
__device__ __forceinline__ void store_llc32(uint* p, uint v) {
    __hip_atomic_store(p, v, __ATOMIC_RELAXED, __HIP_MEMORY_SCOPE_AGENT);
}

// XCC (XCD) id of the CU executing this wave [measured: learn_hip m09]
__device__ __forceinline__ uint get_xcc_id() {
    uint x;
    asm volatile("s_getreg_b32 %0, hwreg(HW_REG_XCC_ID)" : "=s"(x));
    return x;
}

// ---- direct frag-load pipeline primitives (R7-proven, 2-deep) ----
// LOC: PLAIN loads (L1-cacheable) — coherence restored by a per-step
//      buffer_inv (L1-only invalidate, proven neutral-correct in R11).
// !LOC: sc0 sc1 (LLC), R7 verbatim.
template<bool LOC>
__device__ __forceinline__ void frag_issue(uintx4& d0, uintx4& d1, const uint* p) {
    if constexpr (LOC) {
        asm volatile("global_load_dwordx4 %0, %1, off" : "=v"(d0) : "v"(p));
        asm volatile("global_load_dwordx4 %0, %1, off" : "=v"(d1) : "v"(p + 4));
    } else {
        asm volatile("global_load_dwordx4 %0, %1, off sc0 sc1" : "=v"(d0) : "v"(p));
        asm volatile("global_load_dwordx4 %0, %1, off sc0 sc1" : "=v"(d1) : "v"(p + 4));
    }
}
// counted waits, dataflow-tied ("+v": consumers cannot be hoisted — rule 18).
__device__ __forceinline__ void frag_wait2(uintx4& d0, uintx4& d1) {
    asm volatile("s_waitcnt vmcnt(2)" : "+v"(d0), "+v"(d1) :: "memory");
}
__device__ __forceinline__ void frag_wait0(uintx4& d0, uintx4& d1) {
    asm volatile("s_waitcnt vmcnt(0)" : "+v"(d0), "+v"(d1) :: "memory");
}

union pack16 { uint u[4]; bf16x8 v; };
union upk4   { uintx4 u; float4 f; };

__global__ __launch_bounds__(256) void lstm_prep(
    const float* __restrict__ W_ih, const float* __restrict__ W_hh,
    const float* __restrict__ b_ih, const float* __restrict__ b_hh,
    const float* __restrict__ h0, const float* __restrict__ x,
    int two_chain, unsigned char* __restrict__ ws)
{
    int tid = blockIdx.x * 256 + threadIdx.x;       // grid 2048*256 = 524288
    if (tid < 262144) {
        int col = tid >> 8, k = tid & 255;          // col = gate*256+unit
        float v  = W_hh[tid];
        short hi = f2bf(v);
        short lo = f2bf(v - bf2f(hi));
        int g = col >> 8, rem = col & 255;
        int s = rem >> 5, uo = rem & 31, uc = uo >> 4, n = uo & 15;
        int kt = k >> 5, kq = (k >> 3) & 3, j = k & 7;
        size_t unit = ((((size_t)(s * 2 + uc) * 4 + g) * 8 + kt) * 64 + kq * 16 + n);
        ((short*)(ws + WHI_OFF))[unit * 8 + j] = hi;
        ((short*)(ws + WLO_OFF))[unit * 8 + j] = lo;
    }
    if (tid < 524288) {                              // pack h0 -> parity 0
        int row = tid >> 8, k = tid & 255;
        float v  = h0[tid];
        short hi = f2bf(v);
        short lo = f2bf(v - bf2f(hi));
        int kt = k >> 5, kq = (k >> 3) & 3, kk = k & 7;
        int rg, rt, rlow = row & 15;
        if (two_chain) { rg = row >> 5; rt = (row >> 4) & 1; }
        else           { rg = row >> 6; rt = (row >> 4) & 3; }
        const int rgrows = two_chain ? 32 : 64;
        size_t idx = (size_t)rg * ((size_t)rgrows * 256) +
                     (size_t)((((rt * 8 + kt) * 4 + kq) * 16 + rlow) * 8 + kk);
        ((uint*)(ws + HG_OFF))[idx] =
            ((uint)(unsigned short)hi << 16) | (uint)(unsigned short)lo;
    }
    if (tid < 2048 * SEQ) {                          // x transpose -> [t][row]
        int row = tid / SEQ, tt = tid % SEQ;
        ((float*)(ws + XT_OFF))[tt * 2048 + row] = x[tid];
    }
    if (tid < 1024) {
        ((float*)(ws + BB_OFF))[tid] = b_ih[tid] + b_hh[tid];
        ((float*)(ws + WI_OFF))[tid] = W_ih[tid];
    }
    if (tid < 2048) ((uint*)(ws + BAR_OFF))[tid] = 0;   // all barrier slots
}

// ---------------------------------------------------------------------------
// Step loop (R11 math, geometry templated). RGROWS = rows per row-group
// (64 = R11 single-chain; 32 = two-chain, 2 independent rgs per CU so one
// chain's LLC-barrier wait overlaps the other's compute, m114).
// barp  = &bar[this rg's step counter]     (stride differs per variant)
// hg0   = hg + rg*RGROWS*256               (parity offset added inside)
// outp  = out + rg*RGROWS*FLEN
// xTr   = xT + rg*RGROWS
// ---------------------------------------------------------------------------
template<bool LOC, int RGROWS>
__device__ __forceinline__ void run_steps(
    const short* __restrict__ wlo_s, const float* __restrict__ fcw_l,
    float* __restrict__ y_s, const float* __restrict__ xTr,
    uint* __restrict__ barp, uint* __restrict__ hg0, float* __restrict__ outp,
    const bf16x8 (&bhi)[4][8], float (&c)[4],
    const float (&bbg)[4], const float (&wig)[4],
    const float fcb0, const int tid, const int s,
    const int lane, const int quad, const int uc, const int rt,
    const int kq_u, const int kk_u)
{
    const int nof = lane & 15;

    for (int t = 0; t <= SEQ; ++t) {
        const uint par = (uint)t & 1u;
        const uint* __restrict__ hsrc = hg0 + (size_t)par * HG_PAR;
        const uint* fb = hsrc + rt * 4096 + quad * 128 + nof * 8;

        // ---- L1 invalidate: drop lines cached at t-2 (rewritten at t-1).
        if constexpr (LOC)
            asm volatile("buffer_inv" ::: "memory");

        if (t == SEQ) {          // final y only
            if (uc == 0) {
                float p = 0.f;
                #pragma unroll
                for (int kt = 0; kt < 8; ++kt) {
                    uintx4 a0, a1;
                    frag_issue<LOC>(a0, a1, fb + kt * 512);
                    frag_wait0(a0, a1);
                    pack16 ph, pl;
                    ph.u[0] = __builtin_amdgcn_perm(a0[1], a0[0], 0x07060302u);
                    ph.u[1] = __builtin_amdgcn_perm(a0[3], a0[2], 0x07060302u);
                    ph.u[2] = __builtin_amdgcn_perm(a1[1], a1[0], 0x07060302u);
                    ph.u[3] = __builtin_amdgcn_perm(a1[3], a1[2], 0x07060302u);
                    pl.u[0] = __builtin_amdgcn_perm(a0[1], a0[0], 0x05040100u);
                    pl.u[1] = __builtin_amdgcn_perm(a0[3], a0[2], 0x05040100u);
                    pl.u[2] = __builtin_amdgcn_perm(a1[1], a1[0], 0x05040100u);
                    pl.u[3] = __builtin_amdgcn_perm(a1[3], a1[2], 0x05040100u);
                    const float* w = fcw_l + kt * 32 + quad * 8;
                    const float4 w0 = *(const float4*)(w);
                    const float4 w1 = *(const float4*)(w + 4);
                    p += w0.x * (bf2f(ph.v[0]) + bf2f(pl.v[0]));
                    p += w0.y * (bf2f(ph.v[1]) + bf2f(pl.v[1]));
                    p += w0.z * (bf2f(ph.v[2]) + bf2f(pl.v[2]));
                    p += w0.w * (bf2f(ph.v[3]) + bf2f(pl.v[3]));
                    p += w1.x * (bf2f(ph.v[4]) + bf2f(pl.v[4]));
                    p += w1.y * (bf2f(ph.v[5]) + bf2f(pl.v[5]));
                    p += w1.z * (bf2f(ph.v[6]) + bf2f(pl.v[6]));
                    p += w1.w * (bf2f(ph.v[7]) + bf2f(pl.v[7]));
                }
                p += __shfl_xor(p, 16);
                p += __shfl_xor(p, 32);
                if (lane < 16) y_s[rt * 16 + lane] = p;
            }
            __syncthreads();
            if (s == 0 && tid < RGROWS)
                outp[tid * FLEN + (FLEN - 1)] = y_s[tid] + fcb0;
            break;
        }

        const bool fc = (t >= WARM);
        uintx4 xvv;
        if (!fc)         // x(t): own asm load so vmcnt counting stays exact
            asm volatile("global_load_dwordx4 %0, %1, off"
                         : "=v"(xvv)
                         : "v"(xTr + t * 2048 + rt * 16 + quad * 4));

        // ---- 2-deep pipelined frag loads + unpack + MFMA + y-dot ----
        floatx4 acc[4];
        #pragma unroll
        for (int g = 0; g < 4; ++g) acc[g] = (floatx4){0.f, 0.f, 0.f, 0.f};
        float p = 0.f;
        uintx4 A[3][2];
        frag_issue<LOC>(A[0][0], A[0][1], fb + 0 * 512);
        frag_issue<LOC>(A[1][0], A[1][1], fb + 1 * 512);
        #pragma unroll
        for (int kt = 0; kt < 8; ++kt) {
            const int sl = kt % 3;
            uintx4& a0 = A[sl][0];
            uintx4& a1 = A[sl][1];
            if (kt < 7) frag_wait2(a0, a1); else frag_wait0(a0, a1);
            pack16 ph, pl;
            ph.u[0] = __builtin_amdgcn_perm(a0[1], a0[0], 0x07060302u);
            ph.u[1] = __builtin_amdgcn_perm(a0[3], a0[2], 0x07060302u);
            ph.u[2] = __builtin_amdgcn_perm(a1[1], a1[0], 0x07060302u);
            ph.u[3] = __builtin_amdgcn_perm(a1[3], a1[2], 0x07060302u);
            pl.u[0] = __builtin_amdgcn_perm(a0[1], a0[0], 0x05040100u);
            pl.u[1] = __builtin_amdgcn_perm(a0[3], a0[2], 0x05040100u);
            pl.u[2] = __builtin_amdgcn_perm(a1[1], a1[0], 0x05040100u);
            pl.u[3] = __builtin_amdgcn_perm(a1[3], a1[2], 0x05040100u);
            if (fc && uc == 0) {
                const float* w = fcw_l + kt * 32 + quad * 8;
                const float4 w0 = *(const float4*)(w);
                const float4 w1 = *(const float4*)(w + 4);
                p += w0.x * (bf2f(ph.v[0]) + bf2f(pl.v[0]));
                p += w0.y * (bf2f(ph.v[1]) + bf2f(pl.v[1]));
                p += w0.z * (bf2f(ph.v[2]) + bf2f(pl.v[2]));
                p += w0.w * (bf2f(ph.v[3]) + bf2f(pl.v[3]));
                p += w1.x * (bf2f(ph.v[4]) + bf2f(pl.v[4]));
                p += w1.y * (bf2f(ph.v[5]) + bf2f(pl.v[5]));
                p += w1.z * (bf2f(ph.v[6]) + bf2f(pl.v[6]));
                p += w1.w * (bf2f(ph.v[7]) + bf2f(pl.v[7]));
            }
            #pragma unroll
            for (int g = 0; g < 4; ++g) {
                bf16x8 bl = *(const bf16x8*)(wlo_s + ((uc * 4 + g) * 8 + kt) * 512 + lane * 8);
                acc[g] = __builtin_amdgcn_mfma_f32_16x16x32_bf16(ph.v, bhi[g][kt], acc[g], 0, 0, 0);
                acc[g] = __builtin_amdgcn_mfma_f32_16x16x32_bf16(pl.v, bhi[g][kt], acc[g], 0, 0, 0);
                acc[g] = __builtin_amdgcn_mfma_f32_16x16x32_bf16(ph.v, bl,        acc[g], 0, 0, 0);
            }
            if (kt < 6)
                frag_issue<LOC>(A[(kt + 2) % 3][0], A[(kt + 2) % 3][1],
                                fb + (kt + 2) * 512);
        }

        if (fc) {               // y(t-1) exchange within block (single-writer)
            if (uc == 0) {
                p += __shfl_xor(p, 16);
                p += __shfl_xor(p, 32);
                if (lane < 16) y_s[rt * 16 + lane] = p;
            }
            __syncthreads();
            if (t >= WARM + 1 && s == 0 && tid < RGROWS)
                outp[tid * FLEN + (t - (WARM + 1))] = y_s[tid] + fcb0;
        } else {
            // vmcnt is 0 after kt=7's wait; tie xvv so its consumers stay here
            asm volatile("s_waitcnt vmcnt(0)" : "+v"(xvv) :: "memory");
        }

        // ---- elementwise LSTM + h store ----
        uint* __restrict__ hdst = hg0 + (size_t)(1u - par) * HG_PAR;
        upk4 xcv; xcv.u = xvv;
        const float xin[4] = {xcv.f.x, xcv.f.y, xcv.f.z, xcv.f.w};
        #pragma unroll
        for (int i = 0; i < 4; ++i) {
            const int rlow = quad * 4 + i;
            float inr = fc ? (y_s[rt * 16 + rlow] + fcb0) : xin[i];
            float gi = acc[0][i] + bbg[0] + inr * wig[0];
            float gf = acc[1][i] + bbg[1] + inr * wig[1];
            float gg = acc[2][i] + bbg[2] + inr * wig[2];
            float go = acc[3][i] + bbg[3] + inr * wig[3];
            float cn = fast_sig(gf) * c[i] + fast_sig(gi) * fast_tanh(gg);
            c[i] = cn;
            float h = fast_sig(go) * fast_tanh(cn);
            short hi = f2bf(h);
            short lo = f2bf(h - bf2f(hi));
            const uint hval = ((uint)(unsigned short)hi << 16) | (uint)(unsigned short)lo;
            uint* hp = hdst + ((((rt * 8 + s) * 4 + kq_u) * 16 + rlow) * 8 + kk_u);
            if (LOC)    // write-through L1 -> lands (and stays) in shared L2
                __hip_atomic_store(hp, hval, __ATOMIC_RELAXED, __HIP_MEMORY_SCOPE_WORKGROUP);
            else
                store_llc32(hp, hval);
        }
        asm volatile("s_waitcnt vmcnt(0)" ::: "memory");   // h stores acked
        __syncthreads();        // all threads' stores drained before the add

        // ---- inter-block step barrier: agent-scope LLC path (proven) ----
        if (tid == 0) {
            __hip_atomic_fetch_add(barp, 1u, __ATOMIC_RELAXED,
                                   __HIP_MEMORY_SCOPE_AGENT);
            const uint target = 8u * (uint)(t + 1);
            while (__hip_atomic_load(barp, __ATOMIC_RELAXED,
                                     __HIP_MEMORY_SCOPE_AGENT) < target)
                __builtin_amdgcn_s_sleep(1);
        }
        __syncthreads();
    }
}

// ============ Variant 1: R11 verbatim geometry (256 blocks x 512) ============
__global__ void __launch_bounds__(512, 2) lstm_main(
    const float* __restrict__ c0, unsigned char* __restrict__ ws,
    const float* __restrict__ fcw, const float* __restrict__ fcb,
    float* __restrict__ out)
{
    extern __shared__ char smem[];
    short* wlo_s = (short*)smem;                  // 32768 shorts (64 KB)
    float* fcw_l = (float*)(smem + 65536);        // 256 floats (1 KB)
    float* y_s   = (float*)(smem + 66560);        // 64 floats

    const int tid  = threadIdx.x;
    const int blk  = blockIdx.x;
    const int rg   = blk & 31;                    // row-group: 64 rows
    const int s    = blk >> 5;                    // unit-slice: 32 units
    const int wv   = tid >> 6, lane = tid & 63;
    const int quad = lane >> 4, nof = lane & 15;
    const int uc   = wv & 1, rt = wv >> 1;        // rt in [0,4)

    const short* whi_g = (const short*)(ws + WHI_OFF);
    const float* bb    = (const float*)(ws + BB_OFF);
    const float* wi    = (const float*)(ws + WI_OFF);
    const float* xT    = (const float*)(ws + XT_OFF);
    uint* bar          = (uint*)(ws + BAR_OFF);
    uint* hg           = (uint*)(ws + HG_OFF);

    {
        const uint4* src = (const uint4*)(ws + WLO_OFF) + (size_t)s * 4096;
        uint4* dst = (uint4*)wlo_s;
        for (int i = tid; i < 4096; i += 512) dst[i] = src[i];
        if (tid < 256) fcw_l[tid] = fcw[tid];
    }
    bf16x8 bhi[4][8];
    {
        const bf16x8* src = (const bf16x8*)whi_g;
        #pragma unroll
        for (int g = 0; g < 4; ++g)
            #pragma unroll
            for (int kt = 0; kt < 8; ++kt)
                bhi[g][kt] = src[(size_t)(((s * 2 + uc) * 4 + g) * 8 + kt) * 64 + lane];
    }
    const int u = s * 32 + uc * 16 + nof;
    float bbg[4], wig[4];
    #pragma unroll
    for (int g = 0; g < 4; ++g) { bbg[g] = bb[g * 256 + u]; wig[g] = wi[g * 256 + u]; }
    const float fcb0 = fcb[0];
    float c[4];
    #pragma unroll
    for (int i = 0; i < 4; ++i)
        c[i] = c0[(rg * 64 + rt * 16 + quad * 4 + i) * HDIM + u];
    const int kq_u = uc * 2 + (nof >> 3);
    const int kk_u = nof & 7;

    // XCD co-location check (rg-uniform verdict; fallback = LLC)
    if (tid == 0) {
        store_llc32(&bar[rg * 64 + 32 + s], get_xcc_id() + 1u);
        asm volatile("s_waitcnt vmcnt(0)" ::: "memory");
        __hip_atomic_fetch_add(&bar[rg * 64 + 16], 1u, __ATOMIC_RELAXED,
                               __HIP_MEMORY_SCOPE_AGENT);
        while (__hip_atomic_load(&bar[rg * 64 + 16], __ATOMIC_RELAXED,
                                 __HIP_MEMORY_SCOPE_AGENT) < 8u)
            __builtin_amdgcn_s_sleep(1);
        const uint x0 = load_llc32u(&bar[rg * 64 + 32]);
        int ok = 1;
        #pragma unroll
        for (int j = 1; j < 8; ++j)
            ok &= (load_llc32u(&bar[rg * 64 + 32 + j]) == x0);
        ((int*)y_s)[0] = ok;
    }
    __syncthreads();
    const int l2loc = ((int*)y_s)[0];
    __syncthreads();

    uint* barp = bar + rg * 64;
    uint* hg0  = hg + (size_t)rg * 16384;
    float* outp = out + (size_t)rg * 64 * FLEN;
    const float* xTr = xT + rg * 64;

    if (l2loc)
        run_steps<true, 64>(wlo_s, fcw_l, y_s, xTr, barp, hg0, outp, bhi, c,
                            bbg, wig, fcb0, tid, s, lane, quad, uc, rt,
                            kq_u, kk_u);
    else
        run_steps<false, 64>(wlo_s, fcw_l, y_s, xTr, barp, hg0, outp, bhi, c,
                             bbg, wig, fcb0, tid, s, lane, quad, uc, rt,
                             kq_u, kk_u);
}

// ========= Variant 2: two chains per CU (512 blocks x 256 threads) ==========
__global__ void __launch_bounds__(256, 2) lstm_main2(
    const float* __restrict__ c0, unsigned char* __restrict__ ws,
    const float* __restrict__ fcw, const float* __restrict__ fcb,
    float* __restrict__ out)
{
    extern __shared__ char smem[];
    short* wlo_s = (short*)smem;                  // 32768 shorts (64 KB)
    float* fcw_l = (float*)(smem + 65536);        // 256 floats (1 KB)
    float* y_s   = (float*)(smem + 66560);        // 64 floats (32 used)

    const int tid  = threadIdx.x;
    const int blk  = blockIdx.x;
    // rg in [0,64). An rg's 8 blocks differ only in bits 5..7 -> same blk%8
    // -> same XCD under round-robin; CU pair (b, b+256) -> different rg.
    const int rg   = (blk & 31) | (((blk >> 8) & 1) << 5);
    const int s    = (blk >> 5) & 7;
    const int wv   = tid >> 6, lane = tid & 63;
    const int quad = lane >> 4, nof = lane & 15;
    const int uc   = wv & 1, rt = wv >> 1;        // rt in [0,2)

    const short* whi_g = (const short*)(ws + WHI_OFF);
    const float* bb    = (const float*)(ws + BB_OFF);
    const float* wi    = (const float*)(ws + WI_OFF);
    const float* xT    = (const float*)(ws + XT_OFF);
    uint* bar          = (uint*)(ws + BAR_OFF);
    uint* hg           = (uint*)(ws + HG_OFF);

    {
        const uint4* src = (const uint4*)(ws + WLO_OFF) + (size_t)s * 4096;
        uint4* dst = (uint4*)wlo_s;
        for (int i = tid; i < 4096; i += 256) dst[i] = src[i];
        fcw_l[tid] = fcw[tid];
    }
    bf16x8 bhi[4][8];
    {
        const bf16x8* src = (const bf16x8*)whi_g;
        #pragma unroll
        for (int g = 0; g < 4; ++g)
            #pragma unroll
            for (int kt = 0; kt < 8; ++kt)
                bhi[g][kt] = src[(size_t)(((s * 2 + uc) * 4 + g) * 8 + kt) * 64 + lane];
    }
    const int u = s * 32 + uc * 16 + nof;
    float bbg[4], wig[4];
    #pragma unroll
    for (int g = 0; g < 4; ++g) { bbg[g] = bb[g * 256 + u]; wig[g] = wi[g * 256 + u]; }
    const float fcb0 = fcb[0];
    float c[4];
    #pragma unroll
    for (int i = 0; i < 4; ++i)
        c[i] = c0[(rg * 32 + rt * 16 + quad * 4 + i) * HDIM + u];
    const int kq_u = uc * 2 + (nof >> 3);
    const int kk_u = nof & 7;

    // XCD co-location check (rg-uniform verdict; fallback = LLC)
    if (tid == 0) {
        store_llc32(&bar[rg * 32 + 16 + s], get_xcc_id() + 1u);
        asm volatile("s_waitcnt vmcnt(0)" ::: "memory");
        __hip_atomic_fetch_add(&bar[rg * 32 + 8], 1u, __ATOMIC_RELAXED,
                               __HIP_MEMORY_SCOPE_AGENT);
        while (__hip_atomic_load(&bar[rg * 32 + 8], __ATOMIC_RELAXED,
                                 __HIP_MEMORY_SCOPE_AGENT) < 8u)
            __builtin_amdgcn_s_sleep(1);
        const uint x0 = load_llc32u(&bar[rg * 32 + 16]);
        int ok = 1;
        #pragma unroll
        for (int j = 1; j < 8; ++j)
            ok &= (load_llc32u(&bar[rg * 32 + 16 + j]) == x0);
        ((int*)y_s)[0] = ok;
    }
    __syncthreads();
    const int l2loc = ((int*)y_s)[0];
    __syncthreads();

    uint* barp = bar + rg * 32;
    uint* hg0  = hg + (size_t)rg * 8192;
    float* outp = out + (size_t)rg * 32 * FLEN;
    const float* xTr = xT + rg * 32;

    if (l2loc)
        run_steps<true, 32>(wlo_s, fcw_l, y_s, xTr, barp, hg0, outp, bhi, c,
                            bbg, wig, fcb0, tid, s, lane, quad, uc, rt,
                            kq_u, kk_u);
    else
        run_steps<false, 32>(wlo_s, fcw_l, y_s, xTr, barp, hg0, outp, bhi, c,
                             bbg, wig, fcb0, tid, s, lane, quad, uc, rt,
                             kq_u, kk_u);
}

extern "C" void kernel_launch(void* const* d_in, const int* in_sizes, int n_in,
                              void* d_out, int out_size, void* d_ws, size_t ws_size,
                              hipStream_t stream) {
    const float* x    = (const float*)d_in[0];
    const float* h0   = (const float*)d_in[1];
    const float* c0   = (const float*)d_in[2];
    const float* W_ih = (const float*)d_in[3];
    const float* W_hh = (const float*)d_in[4];
    const float* b_ih = (const float*)d_in[5];
    const float* b_hh = (const float*)d_in[6];
    const float* fc_w = (const float*)d_in[7];
    const float* fc_b = (const float*)d_in[8];
    float* out = (float*)d_out;
    unsigned char* ws = (unsigned char*)d_ws;

    // One-time variant selection (pure host queries; graph-capture safe).
    // variant 2 only if the runtime itself certifies 2 blocks/CU at our LDS
    // size — the same internal occupancy calc that gates cooperative launch,
    // so a certified launch cannot be silently rejected (the R5/R13 failure
    // mode: discarded error from an over-capacity cooperative launch).
    static int variant = 0;
    if (!variant) {
        (void)hipFuncSetAttribute((const void*)lstm_main,
                                  hipFuncAttributeMaxDynamicSharedMemorySize, LDS_BYTES);
        (void)hipFuncSetAttribute((const void*)lstm_main2,
                                  hipFuncAttributeMaxDynamicSharedMemorySize, LDS_BYTES);
        int nb = 0;
        hipError_t e = hipOccupancyMaxActiveBlocksPerMultiprocessor(
            &nb, (const void*)lstm_main2, 256, (size_t)LDS_BYTES);
        variant = (e == hipSuccess && nb >= 2) ? 2 : 1;
    }
    const int twoc = (variant == 2) ? 1 : 0;

    lstm_prep<<<2048, 256, 0, stream>>>(W_ih, W_hh, b_ih, b_hh, h0, x, twoc, ws);

    void* args[] = {(void*)&c0, (void*)&ws, (void*)&fc_w, (void*)&fc_b, (void*)&out};
    if (twoc)
        (void)hipLaunchCooperativeKernel((const void*)lstm_main2, dim3(512),
                                         dim3(256), args, LDS_BYTES, stream);
    else
        (void)hipLaunchCooperativeKernel((const void*)lstm_main, dim3(256),
                                         dim3(512), args, LDS_BYTES, stream);
}